// Round 7
// baseline (5069.787 us; speedup 1.0000x reference)
//
#include <hip/hip_runtime.h>
#include <cstdint>
#include <cstddef>

typedef _Float16 half_t;
typedef half_t half2_t __attribute__((ext_vector_type(2)));

static constexpr int TTs = 2048;   // timesteps
static constexpr int BBn = 64;     // batch
static constexpr int DINn = 64;    // input dim
static constexpr int HPn  = 256;   // proj dim
static constexpr int U0c = 135, C0c = 391, R0c = 405;   // layer0
static constexpr int U1c = 89,  C1c = 224, R1c = 267;   // layer1
static constexpr int U2c = 32,  C2c = 121, R2c = 96;    // layer2
static constexpr size_t BTn = (size_t)BBn * TTs;        // 131072

// ---------------- math helpers ----------------
__device__ __forceinline__ float tanh_f(float x) {
    return 1.f - __fdividef(2.f, __expf(2.f * x) + 1.f);
}
__device__ __forceinline__ float sigm_f(float x) {
    return __fdividef(1.f, 1.f + __expf(-x));
}
__device__ __forceinline__ float cfc_comb(float y0, float y1, float y2) {
    float f1 = tanh_f(y0), f2 = tanh_f(y1), ti = sigm_f(y2);
    return f1 + ti * (f2 - f1);
}
// quad butterfly sum via DPP (VALU pipe, no LDS)
__device__ __forceinline__ float qsum(float v) {
    v += __builtin_bit_cast(float, __builtin_amdgcn_update_dpp(
             0, __builtin_bit_cast(int, v), 0xB1, 0xF, 0xF, true));  // [1,0,3,2]
    v += __builtin_bit_cast(float, __builtin_amdgcn_update_dpp(
             0, __builtin_bit_cast(int, v), 0x4E, 0xF, 0xF, true));  // [2,3,0,1]
    return v;
}
__device__ __forceinline__ half2_t h2(unsigned u) { return __builtin_bit_cast(half2_t, u); }

// ---------------- mask dtype probe ----------------
__device__ __forceinline__ int mask_mode(const unsigned char* mp) {
    const unsigned* wp = (const unsigned*)mp;
    bool all01 = true, allf = true;
    for (int k = 0; k < 64; ++k) {
        unsigned w = wp[k];
        all01 = all01 && (w == 0u || w == 1u);
        allf  = allf  && (w == 0u || w == 0x3F800000u);
    }
    if (all01) return 0;
    if (allf)  return 1;
    return 2;
}
__device__ __forceinline__ bool mget(const unsigned char* mp, int mode, int idx) {
    if (mode == 0) return ((const int*)mp)[idx] != 0;
    if (mode == 1) return ((const float*)mp)[idx] != 0.f;
    return mp[idx] != 0;
}

// ---------------- prep: stack + mask weights ----------------
__global__ void k_stack(const float* __restrict__ Wff1, const float* __restrict__ bff1,
                        const float* __restrict__ Wff2, const float* __restrict__ bff2,
                        const float* __restrict__ Wta,  const float* __restrict__ bta,
                        const float* __restrict__ Wtb,  const float* __restrict__ btb,
                        const unsigned char* __restrict__ maskraw,
                        int u, int c, int split,
                        float* __restrict__ outA, float* __restrict__ outB,
                        float* __restrict__ bias_out)
{
    const int mode = mask_mode(maskraw);
    const int total = 3 * u * c + 3 * u;
    for (int idx = blockIdx.x * blockDim.x + threadIdx.x; idx < total;
         idx += gridDim.x * blockDim.x) {
        if (idx < 3 * u * c) {
            int m = idx / (u * c);
            int rem = idx - m * u * c;
            int r = rem / c;
            int k = rem - r * c;
            float v;
            if (m == 2) {
                v = Wta[r * c + k] + Wtb[r * c + k];
            } else {
                bool mk = mget(maskraw, mode, r * c + k);
                float w = (m == 0) ? Wff1[r * c + k] : Wff2[r * c + k];
                v = mk ? w : 0.f;
            }
            int R = m * u + r;
            if (k < split) outA[(size_t)R * split + k] = v;
            else           outB[(size_t)R * (c - split) + (k - split)] = v;
        } else {
            int j = idx - 3 * u * c;
            int m = j / u, r = j - m * u;
            bias_out[j] = (m == 0) ? bff1[r] : ((m == 1) ? bff2[r] : (bta[r] + btb[r]));
        }
    }
}

// ---------------- prep: Wcomb = Wx0s (405x256) @ Wp (256x64) ----------------
__global__ void k_comb(const float* __restrict__ Wx0s, const float* __restrict__ Wp,
                       float* __restrict__ Wcomb)
{
    const int r = blockIdx.x;
    const int d = threadIdx.x;
    float acc = 0.f;
    for (int k = 0; k < HPn; ++k) acc += Wx0s[(size_t)r * HPn + k] * Wp[(size_t)k * DINn + d];
    Wcomb[(size_t)r * DINn + d] = acc;
}

// ---------------- prep: folded bias + Wh2 transpose ----------------
__global__ void k_biasc(const float* __restrict__ Wx0s, const float* __restrict__ bp,
                        const float* __restrict__ b0, float* __restrict__ b0c,
                        const float* __restrict__ Wh2, float* __restrict__ Wh2T)
{
    const int i = blockIdx.x * blockDim.x + threadIdx.x;
    if (i < R0c) {
        float a = b0[i];
        for (int k = 0; k < HPn; ++k) a += Wx0s[(size_t)i * HPn + k] * bp[k];
        b0c[i] = a;
    }
    if (i < HPn * 32) {
        int h = i >> 5, o = i & 31;
        Wh2T[i] = Wh2[(size_t)o * HPn + h];
    }
}

// ---------------- prep: pack weights to padded fp16 ----------------
// W0h (405,224): [Wcb:64 | Wh0s:135 | 0:25]; W1h (267,224); W2h (96,128): [W2s:121|0:7]
__global__ void k_pack(const float* __restrict__ Wcb, const float* __restrict__ Wh0s,
                       const float* __restrict__ W1s, const float* __restrict__ W2s,
                       half_t* __restrict__ W0h, half_t* __restrict__ W1h,
                       half_t* __restrict__ W2h)
{
    const int N0 = R0c * 224, N1 = R1c * 224, N2 = R2c * 128;
    for (int idx = blockIdx.x * blockDim.x + threadIdx.x; idx < N0 + N1 + N2;
         idx += gridDim.x * blockDim.x) {
        if (idx < N0) {
            int r = idx / 224, c = idx - r * 224;
            float v = (c < 64) ? Wcb[(size_t)r * 64 + c]
                               : ((c < 199) ? Wh0s[(size_t)r * 135 + (c - 64)] : 0.f);
            W0h[idx] = (half_t)v;
        } else if (idx < N0 + N1) {
            int i = idx - N0;
            W1h[i] = (half_t)W1s[i];
        } else {
            int i = idx - N0 - N1;
            int r = i / 128, c = i - r * 128;
            W2h[i] = (half_t)((c < 121) ? W2s[(size_t)r * 121 + c] : 0.f);
        }
    }
}

#define PIN4(v) asm volatile("" : "+v"((v).x), "+v"((v).y), "+v"((v).z), "+v"((v).w))
// light barrier: LDS-ordering only; vmem loads/stores stay in flight (no
// cross-wave communication through global memory inside the loop).
#define BAR() asm volatile("s_waitcnt lgkmcnt(0)\n\ts_barrier" ::: "memory")

#define ROW7(nm) uint4 nm##_0, nm##_1, nm##_2, nm##_3, nm##_4, nm##_5, nm##_6
#define LD7(nm, baseptr) { const uint4* _p = (const uint4*)(baseptr); \
    nm##_0=_p[0]; nm##_1=_p[1]; nm##_2=_p[2]; nm##_3=_p[3]; nm##_4=_p[4]; nm##_5=_p[5]; nm##_6=_p[6]; }
#define LD4(nm, baseptr) { const uint4* _p = (const uint4*)(baseptr); \
    nm##_0=_p[0]; nm##_1=_p[1]; nm##_2=_p[2]; nm##_3=_p[3]; }
#define ZERO7(nm) nm##_0=z4u; nm##_1=z4u; nm##_2=z4u; nm##_3=z4u; nm##_4=z4u; nm##_5=z4u; nm##_6=z4u
#define PIN7(nm) PIN4(nm##_0); PIN4(nm##_1); PIN4(nm##_2); PIN4(nm##_3); PIN4(nm##_4); PIN4(nm##_5); PIN4(nm##_6)
#define D4(acc, W, F) \
    acc = __builtin_amdgcn_fdot2(h2((W).x), __builtin_bit_cast(half2_t,(F).x), acc, false); \
    acc = __builtin_amdgcn_fdot2(h2((W).y), __builtin_bit_cast(half2_t,(F).y), acc, false); \
    acc = __builtin_amdgcn_fdot2(h2((W).z), __builtin_bit_cast(half2_t,(F).z), acc, false); \
    acc = __builtin_amdgcn_fdot2(h2((W).w), __builtin_bit_cast(half2_t,(F).w), acc, false);
#define DROW7(acc, nm) D4(acc,nm##_0,f0) D4(acc,nm##_1,f1) D4(acc,nm##_2,f2) \
    D4(acc,nm##_3,f3) D4(acc,nm##_4,f4) D4(acc,nm##_5,f5) D4(acc,nm##_6,f6)
#define DROW4(acc, nm) D4(acc,nm##_0,f0) D4(acc,nm##_1,f1) D4(acc,nm##_2,f2) D4(acc,nm##_3,f3)

// ---------------- the recurrent scan: 64 blocks x 256 threads ----------------
// Quad-per-unit column-split: s = t>>2 (0..63), q = t&3 (56-half chunk).
// Each quad owns exactly 4 units (64*4 = 256 = 135 L0 + 89 L1 + 32 L2):
//   L0 {s, 64+s} (phase A), L1 {s} (phase B), plus role:
//   s<25       -> L1 64+s          (phase B)
//   32<=s<39   -> L0 128+(s-32)    (phase A)
//   else       -> L2 uC            (phase C)
// 84 named uint4 (336 dwords) of fp16 weights; __launch_bounds__(256,1)
// gives a 512-reg budget so residency is pressure-free. Light barriers keep
// the per-step x prefetch in flight across phases.
__global__ __launch_bounds__(256, 1) void k_scan(
    const half_t* __restrict__ W0h,   // (405,224)
    const half_t* __restrict__ W1h,   // (267,224)
    const half_t* __restrict__ W2h,   // (96,128)
    const float* __restrict__ b0c,    // (405)
    const float* __restrict__ b1s,    // (267)
    const float* __restrict__ b2s,    // (96)
    const float* __restrict__ x,      // (B,T,64)
    float* __restrict__ cfc)          // (B,T,32)
{
    const int t = threadIdx.x;
    const int b = blockIdx.x;
    const int s = t >> 2;     // slot 0..63
    const int q = t & 3;      // column chunk

    __shared__ float4 z0v[2][28];   // 224 halfs: [x:64 | h0:135 | 0:25]
    __shared__ float4 z1v[2][28];   // 224 halfs: [h0:135 | h1:89]
    __shared__ float4 z2v[2][16];   // 128 halfs: [h1:89 | h2:32 | 0:7]

    {
        float4* zz = (float4*)z0v;
        for (int i = t; i < 56 + 56 + 32; i += 256) zz[i] = make_float4(0.f, 0.f, 0.f, 0.f);
    }

    // ---- roles ----
    const bool isB2 = (s < 25);
    const bool isA3 = (s >= 32 && s < 39);
    const bool isC  = !isB2 && !isA3;                     // s in [25,32) or [39,64)
    const int uC = isC ? ((s < 32) ? (s - 25) : (7 + (s - 39))) : 0;

    // ---- weights: 84 named uint4 (336 dwords), fp16 half2-packed ----
    ROW7(wA1r0); ROW7(wA1r1); ROW7(wA1r2);    // L0 unit s
    ROW7(wA2r0); ROW7(wA2r1); ROW7(wA2r2);    // L0 unit 64+s
    ROW7(wB1r0); ROW7(wB1r1); ROW7(wB1r2);    // L1 unit s
    ROW7(wXr0);  ROW7(wXr1);  ROW7(wXr2);     // role unit
    {
        const size_t cq = 56 * q;
        LD7(wA1r0, W0h + (size_t)(s      ) * 224 + cq);
        LD7(wA1r1, W0h + (size_t)(s + 135) * 224 + cq);
        LD7(wA1r2, W0h + (size_t)(s + 270) * 224 + cq);
        LD7(wA2r0, W0h + (size_t)(s +  64) * 224 + cq);
        LD7(wA2r1, W0h + (size_t)(s + 199) * 224 + cq);
        LD7(wA2r2, W0h + (size_t)(s + 334) * 224 + cq);
        LD7(wB1r0, W1h + (size_t)(s      ) * 224 + cq);
        LD7(wB1r1, W1h + (size_t)(s +  89) * 224 + cq);
        LD7(wB1r2, W1h + (size_t)(s + 178) * 224 + cq);
        const uint4 z4u = make_uint4(0u, 0u, 0u, 0u);
        ZERO7(wXr0); ZERO7(wXr1); ZERO7(wXr2);
        if (isB2) {
            LD7(wXr0, W1h + (size_t)(s +  64) * 224 + cq);
            LD7(wXr1, W1h + (size_t)(s + 153) * 224 + cq);
            LD7(wXr2, W1h + (size_t)(s + 242) * 224 + cq);
        } else if (isA3) {
            LD7(wXr0, W0h + (size_t)(s +  96) * 224 + cq);
            LD7(wXr1, W0h + (size_t)(s + 231) * 224 + cq);
            LD7(wXr2, W0h + (size_t)(s + 366) * 224 + cq);
        } else {
            const size_t cq2 = 32 * q;
            LD4(wXr0, W2h + (size_t)(uC     ) * 128 + cq2);
            LD4(wXr1, W2h + (size_t)(uC + 32) * 128 + cq2);
            LD4(wXr2, W2h + (size_t)(uC + 64) * 128 + cq2);
        }
    }
    PIN7(wA1r0); PIN7(wA1r1); PIN7(wA1r2);
    PIN7(wA2r0); PIN7(wA2r1); PIN7(wA2r2);
    PIN7(wB1r0); PIN7(wB1r1); PIN7(wB1r2);
    PIN7(wXr0);  PIN7(wXr1);  PIN7(wXr2);

    // ---- biases ----
    const float bA10 = b0c[s],      bA11 = b0c[135 + s], bA12 = b0c[270 + s];
    const float bA20 = b0c[64 + s], bA21 = b0c[199 + s], bA22 = b0c[334 + s];
    const float bB10 = b1s[s],      bB11 = b1s[89 + s],  bB12 = b1s[178 + s];
    float bX0, bX1, bX2;
    if (isB2)      { bX0 = b1s[64 + s]; bX1 = b1s[153 + s]; bX2 = b1s[242 + s]; }
    else if (isA3) { bX0 = b0c[96 + s]; bX1 = b0c[231 + s]; bX2 = b0c[366 + s]; }
    else           { bX0 = b2s[uC];     bX1 = b2s[32 + uC]; bX2 = b2s[64 + uC]; }

    const float* xb = x + (size_t)b * TTs * DINn;
    float* cfb = cfc + (size_t)b * TTs * 32;

    __syncthreads();
    if (t < 64) ((half_t*)&z0v[0][0])[t] = (half_t)xb[t];   // x(0)
    __syncthreads();

#pragma unroll 1
    for (int ts = 0; ts < TTs; ++ts) {
        const int p = ts & 1;
        half_t* z0n = (half_t*)&z0v[p ^ 1][0];
        half_t* z1c = (half_t*)&z1v[p][0];
        half_t* z1n = (half_t*)&z1v[p ^ 1][0];
        half_t* z2c = (half_t*)&z2v[p][0];
        half_t* z2n = (half_t*)&z2v[p ^ 1][0];

        float xnext = 0.f;
        if (t < 64) {
            int tn = (ts + 1 < TTs) ? ts + 1 : ts;
            xnext = xb[(size_t)tn * DINn + t];
        }

        // ================= phase A : layer0 over z0=[x|h0] =================
        {
            const float4* zc = &z0v[p][q * 7];
            float4 f0 = zc[0], f1 = zc[1], f2 = zc[2], f3 = zc[3],
                   f4 = zc[4], f5 = zc[5], f6 = zc[6];
            float a0 = 0.f, a1 = 0.f, a2 = 0.f, a3 = 0.f, a4 = 0.f, a5 = 0.f;
            DROW7(a0, wA1r0) DROW7(a1, wA1r1) DROW7(a2, wA1r2)
            DROW7(a3, wA2r0) DROW7(a4, wA2r1) DROW7(a5, wA2r2)
            float c0 = 0.f, c1 = 0.f, c2 = 0.f;
            if (isA3) { DROW7(c0, wXr0) DROW7(c1, wXr1) DROW7(c2, wXr2) }
            a0 = qsum(a0); a1 = qsum(a1); a2 = qsum(a2);
            a3 = qsum(a3); a4 = qsum(a4); a5 = qsum(a5);
            if (q == 0) {
                float h1v = cfc_comb(a0 + bA10, a1 + bA11, a2 + bA12);
                half_t hh1 = (half_t)h1v;
                z1c[s]       = hh1;
                z0n[64 + s]  = hh1;
                float h2v = cfc_comb(a3 + bA20, a4 + bA21, a5 + bA22);
                half_t hh2 = (half_t)h2v;
                z1c[64 + s]  = hh2;
                z0n[128 + s] = hh2;
            }
            if (isA3) {
                c0 = qsum(c0); c1 = qsum(c1); c2 = qsum(c2);
                if (q == 0) {
                    float hv = cfc_comb(c0 + bX0, c1 + bX1, c2 + bX2);
                    half_t hh = (half_t)hv;
                    z1c[96 + s]  = hh;
                    z0n[160 + s] = hh;
                }
            }
        }
        BAR();

        // ================= phase B : layer1 over z1=[h0|h1] ================
        {
            const float4* zc = &z1v[p][q * 7];
            float4 f0 = zc[0], f1 = zc[1], f2 = zc[2], f3 = zc[3],
                   f4 = zc[4], f5 = zc[5], f6 = zc[6];
            float a0 = 0.f, a1 = 0.f, a2 = 0.f;
            DROW7(a0, wB1r0) DROW7(a1, wB1r1) DROW7(a2, wB1r2)
            float c0 = 0.f, c1 = 0.f, c2 = 0.f;
            if (isB2) { DROW7(c0, wXr0) DROW7(c1, wXr1) DROW7(c2, wXr2) }
            a0 = qsum(a0); a1 = qsum(a1); a2 = qsum(a2);
            if (q == 0) {
                float hv = cfc_comb(a0 + bB10, a1 + bB11, a2 + bB12);
                half_t hh = (half_t)hv;
                z2c[s]       = hh;
                z1n[135 + s] = hh;
            }
            if (isB2) {
                c0 = qsum(c0); c1 = qsum(c1); c2 = qsum(c2);
                if (q == 0) {
                    float hv = cfc_comb(c0 + bX0, c1 + bX1, c2 + bX2);
                    half_t hh = (half_t)hv;
                    z2c[64 + s]  = hh;
                    z1n[199 + s] = hh;
                }
            }
        }
        BAR();

        // ================= phase C : layer2 over z2=[h1|h2] ================
        if (isC) {
            const float4* zc = &z2v[p][q * 4];
            float4 f0 = zc[0], f1 = zc[1], f2 = zc[2], f3 = zc[3];
            float a0 = 0.f, a1 = 0.f, a2 = 0.f;
            DROW4(a0, wXr0) DROW4(a1, wXr1) DROW4(a2, wXr2)
            a0 = qsum(a0); a1 = qsum(a1); a2 = qsum(a2);
            if (q == 0) {
                float hv = cfc_comb(a0 + bX0, a1 + bX1, a2 + bX2);
                z2n[89 + uC] = (half_t)hv;
                cfb[(size_t)ts * 32 + uC] = hv;
            }
        }
        if (t < 64) z0n[t] = (half_t)xnext;   // x(ts+1)
        BAR();
    }
}

// ---------------- head: in-place gelu(cfc@Wh1.T+bh1)@Wh2.T + bh2 ----------------
__global__ __launch_bounds__(256) void k_head(float* io,
                                              const float* __restrict__ Wh1,
                                              const float* __restrict__ bh1,
                                              const float* __restrict__ Wh2T,
                                              const float* __restrict__ bh2)
{
    const int bt = blockIdx.x * 256 + threadIdx.x;
    float c32[32];
    const float4* cp = (const float4*)(io + (size_t)bt * 32);
#pragma unroll
    for (int k = 0; k < 8; ++k) {
        float4 v = cp[k];
        c32[4 * k] = v.x; c32[4 * k + 1] = v.y; c32[4 * k + 2] = v.z; c32[4 * k + 3] = v.w;
    }
    float acc[32];
#pragma unroll
    for (int o = 0; o < 32; ++o) acc[o] = bh2[o];
#pragma unroll 1
    for (int h = 0; h < HPn; ++h) {
        float ss = bh1[h];
        const float* w1r = Wh1 + (size_t)h * 32;
#pragma unroll
        for (int k = 0; k < 32; ++k) ss += c32[k] * w1r[k];
        float g = 0.5f * ss * (1.f + erff(ss * 0.70710678118654752440f));
        const float* w2r = Wh2T + (size_t)h * 32;
#pragma unroll
        for (int o = 0; o < 32; ++o) acc[o] += g * w2r[o];
    }
    float4* op = (float4*)(io + (size_t)bt * 32);
#pragma unroll
    for (int k = 0; k < 8; ++k) {
        float4 v;
        v.x = acc[4 * k]; v.y = acc[4 * k + 1]; v.z = acc[4 * k + 2]; v.w = acc[4 * k + 3];
        op[k] = v;
    }
}

// ---------------- launch ----------------
extern "C" void kernel_launch(void* const* d_in, const int* in_sizes, int n_in,
                              void* d_out, int out_size, void* d_ws, size_t ws_size,
                              hipStream_t stream)
{
    (void)in_sizes; (void)n_in; (void)out_size; (void)ws_size;
    const float* x      = (const float*)d_in[0];
    const float* Wp     = (const float*)d_in[1];
    const float* bp     = (const float*)d_in[2];
    const float* Wff1_0 = (const float*)d_in[3];
    const float* bff1_0 = (const float*)d_in[4];
    const float* Wff2_0 = (const float*)d_in[5];
    const float* bff2_0 = (const float*)d_in[6];
    const float* Wta_0  = (const float*)d_in[7];
    const float* bta_0  = (const float*)d_in[8];
    const float* Wtb_0  = (const float*)d_in[9];
    const float* btb_0  = (const float*)d_in[10];
    const unsigned char* mask_0 = (const unsigned char*)d_in[11];
    const float* Wff1_1 = (const float*)d_in[12];
    const float* bff1_1 = (const float*)d_in[13];
    const float* Wff2_1 = (const float*)d_in[14];
    const float* bff2_1 = (const float*)d_in[15];
    const float* Wta_1  = (const float*)d_in[16];
    const float* bta_1  = (const float*)d_in[17];
    const float* Wtb_1  = (const float*)d_in[18];
    const float* btb_1  = (const float*)d_in[19];
    const unsigned char* mask_1 = (const unsigned char*)d_in[20];
    const float* Wff1_2 = (const float*)d_in[21];
    const float* bff1_2 = (const float*)d_in[22];
    const float* Wff2_2 = (const float*)d_in[23];
    const float* bff2_2 = (const float*)d_in[24];
    const float* Wta_2  = (const float*)d_in[25];
    const float* bta_2  = (const float*)d_in[26];
    const float* Wtb_2  = (const float*)d_in[27];
    const float* btb_2  = (const float*)d_in[28];
    const unsigned char* mask_2 = (const unsigned char*)d_in[29];
    const float* Wh1    = (const float*)d_in[30];
    const float* bh1    = (const float*)d_in[31];
    const float* Wh2    = (const float*)d_in[32];
    const float* bh2    = (const float*)d_in[33];

    float* ws = (float*)d_ws;
    size_t o = 0;
    float* Wh0s = ws + o; o += (size_t)R0c * U0c;
    float* Wx0s = ws + o; o += (size_t)R0c * HPn;
    float* b0s  = ws + o; o += R0c; o += 3;
    float* Wcb  = ws + o; o += (size_t)R0c * DINn;
    float* b0c  = ws + o; o += R0c; o += 3;
    float* W1s  = ws + o; o += (size_t)R1c * C1c;
    float* b1s  = ws + o; o += R1c; o += 1;
    float* W2s  = ws + o; o += (size_t)R2c * C2c;
    float* b2s  = ws + o; o += R2c;
    float* Wh2T = ws + o; o += (size_t)HPn * 32;
    half_t* W0h = (half_t*)(ws + o); o += (size_t)R0c * 224 / 2;
    half_t* W1h = (half_t*)(ws + o); o += (size_t)R1c * 224 / 2;
    half_t* W2h = (half_t*)(ws + o); o += (size_t)R2c * 128 / 2;

    k_stack<<<128, 256, 0, stream>>>(Wff1_0, bff1_0, Wff2_0, bff2_0, Wta_0, bta_0, Wtb_0, btb_0,
                                     mask_0, U0c, C0c, HPn, Wx0s, Wh0s, b0s);
    k_stack<<<64, 256, 0, stream>>>(Wff1_1, bff1_1, Wff2_1, bff2_1, Wta_1, bta_1, Wtb_1, btb_1,
                                    mask_1, U1c, C1c, C1c, W1s, W1s, b1s);
    k_stack<<<16, 256, 0, stream>>>(Wff1_2, bff1_2, Wff2_2, bff2_2, Wta_2, bta_2, Wtb_2, btb_2,
                                    mask_2, U2c, C2c, C2c, W2s, W2s, b2s);
    k_comb<<<R0c, DINn, 0, stream>>>(Wx0s, Wp, Wcb);
    k_biasc<<<32, 256, 0, stream>>>(Wx0s, bp, b0s, b0c, Wh2, Wh2T);
    k_pack<<<320, 256, 0, stream>>>(Wcb, Wh0s, W1s, W2s, W0h, W1h, W2h);
    k_scan<<<BBn, 256, 0, stream>>>(W0h, W1h, W2h, b0c, b1s, b2s, x, (float*)d_out);
    k_head<<<(int)(BTn / 256), 256, 0, stream>>>((float*)d_out, Wh1, bh1, Wh2T, bh2);
}

// Round 8
// 3248.734 us; speedup vs baseline: 1.5605x; 1.5605x over previous
//
#include <hip/hip_runtime.h>
#include <cstdint>
#include <cstddef>

typedef _Float16 half_t;
typedef half_t half2_t __attribute__((ext_vector_type(2)));

static constexpr int TTs = 2048;   // timesteps
static constexpr int BBn = 64;     // batch
static constexpr int DINn = 64;    // input dim
static constexpr int HPn  = 256;   // proj dim
static constexpr int U0c = 135, C0c = 391, R0c = 405;   // layer0
static constexpr int U1c = 89,  C1c = 224, R1c = 267;   // layer1
static constexpr int U2c = 32,  C2c = 121, R2c = 96;    // layer2
static constexpr size_t BTn = (size_t)BBn * TTs;        // 131072

// ---------------- math helpers ----------------
__device__ __forceinline__ float tanh_f(float x) {
    return 1.f - __fdividef(2.f, __expf(2.f * x) + 1.f);
}
__device__ __forceinline__ float sigm_f(float x) {
    return __fdividef(1.f, 1.f + __expf(-x));
}
__device__ __forceinline__ float cfc_comb(float y0, float y1, float y2) {
    float f1 = tanh_f(y0), f2 = tanh_f(y1), ti = sigm_f(y2);
    return f1 + ti * (f2 - f1);
}
// quad butterfly sum via DPP (VALU pipe, no LDS)
__device__ __forceinline__ float qsum(float v) {
    v += __builtin_bit_cast(float, __builtin_amdgcn_update_dpp(
             0, __builtin_bit_cast(int, v), 0xB1, 0xF, 0xF, true));  // [1,0,3,2]
    v += __builtin_bit_cast(float, __builtin_amdgcn_update_dpp(
             0, __builtin_bit_cast(int, v), 0x4E, 0xF, 0xF, true));  // [2,3,0,1]
    return v;
}
__device__ __forceinline__ half2_t h2(unsigned u) { return __builtin_bit_cast(half2_t, u); }

// ---------------- mask dtype probe ----------------
__device__ __forceinline__ int mask_mode(const unsigned char* mp) {
    const unsigned* wp = (const unsigned*)mp;
    bool all01 = true, allf = true;
    for (int k = 0; k < 64; ++k) {
        unsigned w = wp[k];
        all01 = all01 && (w == 0u || w == 1u);
        allf  = allf  && (w == 0u || w == 0x3F800000u);
    }
    if (all01) return 0;
    if (allf)  return 1;
    return 2;
}
__device__ __forceinline__ bool mget(const unsigned char* mp, int mode, int idx) {
    if (mode == 0) return ((const int*)mp)[idx] != 0;
    if (mode == 1) return ((const float*)mp)[idx] != 0.f;
    return mp[idx] != 0;
}

// ---------------- prep: stack + mask weights ----------------
__global__ void k_stack(const float* __restrict__ Wff1, const float* __restrict__ bff1,
                        const float* __restrict__ Wff2, const float* __restrict__ bff2,
                        const float* __restrict__ Wta,  const float* __restrict__ bta,
                        const float* __restrict__ Wtb,  const float* __restrict__ btb,
                        const unsigned char* __restrict__ maskraw,
                        int u, int c, int split,
                        float* __restrict__ outA, float* __restrict__ outB,
                        float* __restrict__ bias_out)
{
    const int mode = mask_mode(maskraw);
    const int total = 3 * u * c + 3 * u;
    for (int idx = blockIdx.x * blockDim.x + threadIdx.x; idx < total;
         idx += gridDim.x * blockDim.x) {
        if (idx < 3 * u * c) {
            int m = idx / (u * c);
            int rem = idx - m * u * c;
            int r = rem / c;
            int k = rem - r * c;
            float v;
            if (m == 2) {
                v = Wta[r * c + k] + Wtb[r * c + k];
            } else {
                bool mk = mget(maskraw, mode, r * c + k);
                float w = (m == 0) ? Wff1[r * c + k] : Wff2[r * c + k];
                v = mk ? w : 0.f;
            }
            int R = m * u + r;
            if (k < split) outA[(size_t)R * split + k] = v;
            else           outB[(size_t)R * (c - split) + (k - split)] = v;
        } else {
            int j = idx - 3 * u * c;
            int m = j / u, r = j - m * u;
            bias_out[j] = (m == 0) ? bff1[r] : ((m == 1) ? bff2[r] : (bta[r] + btb[r]));
        }
    }
}

// ---------------- prep: Wcomb = Wx0s (405x256) @ Wp (256x64) ----------------
__global__ void k_comb(const float* __restrict__ Wx0s, const float* __restrict__ Wp,
                       float* __restrict__ Wcomb)
{
    const int r = blockIdx.x;
    const int d = threadIdx.x;
    float acc = 0.f;
    for (int k = 0; k < HPn; ++k) acc += Wx0s[(size_t)r * HPn + k] * Wp[(size_t)k * DINn + d];
    Wcomb[(size_t)r * DINn + d] = acc;
}

// ---------------- prep: folded bias + Wh2 transpose ----------------
__global__ void k_biasc(const float* __restrict__ Wx0s, const float* __restrict__ bp,
                        const float* __restrict__ b0, float* __restrict__ b0c,
                        const float* __restrict__ Wh2, float* __restrict__ Wh2T)
{
    const int i = blockIdx.x * blockDim.x + threadIdx.x;
    if (i < R0c) {
        float a = b0[i];
        for (int k = 0; k < HPn; ++k) a += Wx0s[(size_t)i * HPn + k] * bp[k];
        b0c[i] = a;
    }
    if (i < HPn * 32) {
        int h = i >> 5, o = i & 31;
        Wh2T[i] = Wh2[(size_t)o * HPn + h];
    }
}

// ---------------- prep: pack weights to padded fp16 ----------------
// W0h (405,224): [Wcb:64 | Wh0s:135 | 0:25]; W1h (267,224); W2h (96,128): [W2s:121|0:7]
__global__ void k_pack(const float* __restrict__ Wcb, const float* __restrict__ Wh0s,
                       const float* __restrict__ W1s, const float* __restrict__ W2s,
                       half_t* __restrict__ W0h, half_t* __restrict__ W1h,
                       half_t* __restrict__ W2h)
{
    const int N0 = R0c * 224, N1 = R1c * 224, N2 = R2c * 128;
    for (int idx = blockIdx.x * blockDim.x + threadIdx.x; idx < N0 + N1 + N2;
         idx += gridDim.x * blockDim.x) {
        if (idx < N0) {
            int r = idx / 224, c = idx - r * 224;
            float v = (c < 64) ? Wcb[(size_t)r * 64 + c]
                               : ((c < 199) ? Wh0s[(size_t)r * 135 + (c - 64)] : 0.f);
            W0h[idx] = (half_t)v;
        } else if (idx < N0 + N1) {
            int i = idx - N0;
            W1h[i] = (half_t)W1s[i];
        } else {
            int i = idx - N0 - N1;
            int r = i / 128, c = i - r * 128;
            W2h[i] = (half_t)((c < 121) ? W2s[(size_t)r * 121 + c] : 0.f);
        }
    }
}

#define PIN4(v) asm volatile("" : "+v"((v).x), "+v"((v).y), "+v"((v).z), "+v"((v).w))
// light barrier: LDS-ordering only; vmem stays in flight.
#define BAR() asm volatile("s_waitcnt lgkmcnt(0)\n\ts_barrier" ::: "memory")

#define LD7(a,b,c,d,e,f,g, ptr) { const uint4* _p = (const uint4*)(ptr); \
    a=_p[0]; b=_p[1]; c=_p[2]; d=_p[3]; e=_p[4]; f=_p[5]; g=_p[6]; }
#define LD4(a,b,c,d, ptr) { const uint4* _p = (const uint4*)(ptr); \
    a=_p[0]; b=_p[1]; c=_p[2]; d=_p[3]; }
#define Z7(a,b,c,d,e,f,g) a=z4u; b=z4u; c=z4u; d=z4u; e=z4u; f=z4u; g=z4u;
#define D4(acc, W, F) \
    acc = __builtin_amdgcn_fdot2(h2((W).x), __builtin_bit_cast(half2_t,(F).x), acc, false); \
    acc = __builtin_amdgcn_fdot2(h2((W).y), __builtin_bit_cast(half2_t,(F).y), acc, false); \
    acc = __builtin_amdgcn_fdot2(h2((W).z), __builtin_bit_cast(half2_t,(F).z), acc, false); \
    acc = __builtin_amdgcn_fdot2(h2((W).w), __builtin_bit_cast(half2_t,(F).w), acc, false);
#define DR7(acc, A,B,C,D,E,F,G) D4(acc,A,f0) D4(acc,B,f1) D4(acc,C,f2) \
    D4(acc,D,f3) D4(acc,E,f4) D4(acc,F,f5) D4(acc,G,f6)
#define DR4(acc, A,B,C,D) D4(acc,A,f0) D4(acc,B,f1) D4(acc,C,f2) D4(acc,D,f3)

// ---------------- pipelined recurrent scan: 64 blocks x 512 threads ----------
// The CfC stack is a pipeline: h0(k+1)=f0(x(k+1)? no: x_k,h0_k); h1 lags h0 one
// step; h2 lags h1. Iteration k runs concurrently:
//   waves 0-3 (L0): h0^{k+1} = f0(x_k, h0^k)           reads z0[p]
//   waves 4-6 (L1): h1^{k}   = f1(h0^k, h1^{k-1})      reads z1[p]   (write-gated k>=1)
//   wave  7  (L2): h2^{k-1} = f2(h1^{k-1}, h2^{k-2})   reads z2[p]   (write-gated k>=2)
//                  + 7 leftover L0 units + x staging
// All consumers read values >=1 iteration old -> ONE barrier per iteration with
// double-buffered state. 2050 iterations total. Weights: one SHARED set of 45
// named uint4 per lane (union across roles, <=180 dwords).
__global__ __launch_bounds__(512) void k_scan(
    const half_t* __restrict__ W0h,   // (405,224)
    const half_t* __restrict__ W1h,   // (267,224)
    const half_t* __restrict__ W2h,   // (96,128)
    const float* __restrict__ b0c,    // (405)
    const float* __restrict__ b1s,    // (267)
    const float* __restrict__ b2s,    // (96)
    const float* __restrict__ x,      // (B,T,64)
    float* __restrict__ cfc)          // (B,T,32)
{
    const int t = threadIdx.x;
    const int b = blockIdx.x;
    const int q = t & 3;

    __shared__ float4 z0v[2][28];   // 224 halfs: [x:64 | h0:135 | 0:25]
    __shared__ float4 z1v[2][28];   // 224 halfs: [h0:135 | h1:89]
    __shared__ float4 z2v[2][16];   // 128 halfs: [h1:89 | h2:32 | 0:7]

    {
        float4* zz = (float4*)z0v;
        for (int i = t; i < 144; i += 512) zz[i] = make_float4(0.f, 0.f, 0.f, 0.f);
    }

    const bool gL0 = (t < 256);
    const bool gL1 = (t >= 256) && (t < 448);
    const int s0 = t >> 2;            // 0..63   (L0)
    const int s1 = (t - 256) >> 2;    // 0..47   (L1)
    const int s2 = (t - 448) >> 2;    // 0..15   (L2)
    const int xi = t - 448;           // wave 7 stages x

    // ---- shared weight set: 45 named uint4 ----
    const uint4 z4u = make_uint4(0u, 0u, 0u, 0u);
    uint4 w00,w01,w02,w03,w04,w05,w06, w07,w08,w09,w10,w11,w12,w13;
    uint4 w14,w15,w16,w17,w18,w19,w20, w21,w22,w23,w24,w25,w26,w27;
    uint4 w28,w29,w30,w31,w32,w33,w34, w35,w36,w37,w38,w39,w40,w41;
    uint4 w42,w43,w44;
    Z7(w00,w01,w02,w03,w04,w05,w06) Z7(w07,w08,w09,w10,w11,w12,w13)
    Z7(w14,w15,w16,w17,w18,w19,w20) Z7(w21,w22,w23,w24,w25,w26,w27)
    Z7(w28,w29,w30,w31,w32,w33,w34) Z7(w35,w36,w37,w38,w39,w40,w41)
    w42 = z4u; w43 = z4u; w44 = z4u;

    float bA0=0.f,bA1=0.f,bA2=0.f, bB0=0.f,bB1=0.f,bB2=0.f, bX0=0.f,bX1=0.f,bX2=0.f;
    bool vB = false, vX = false;

    if (gL0) {
        const size_t cq = 56 * q;
        LD7(w00,w01,w02,w03,w04,w05,w06, W0h + (size_t)(s0      ) * 224 + cq)
        LD7(w07,w08,w09,w10,w11,w12,w13, W0h + (size_t)(s0 + 135) * 224 + cq)
        LD7(w14,w15,w16,w17,w18,w19,w20, W0h + (size_t)(s0 + 270) * 224 + cq)
        LD7(w21,w22,w23,w24,w25,w26,w27, W0h + (size_t)(s0 +  64) * 224 + cq)
        LD7(w28,w29,w30,w31,w32,w33,w34, W0h + (size_t)(s0 + 199) * 224 + cq)
        LD7(w35,w36,w37,w38,w39,w40,w41, W0h + (size_t)(s0 + 334) * 224 + cq)
        bA0 = b0c[s0];      bA1 = b0c[135 + s0]; bA2 = b0c[270 + s0];
        bB0 = b0c[64 + s0]; bB1 = b0c[199 + s0]; bB2 = b0c[334 + s0];
        vB = true;
    } else if (gL1) {
        const size_t cq = 56 * q;
        const bool vA = (s1 <= 44);
        vB = (s1 <= 43);
        const int ua = vA ? s1 : 0;
        const int ub = vB ? 45 + s1 : 0;
        LD7(w00,w01,w02,w03,w04,w05,w06, W1h + (size_t)(ua      ) * 224 + cq)
        LD7(w07,w08,w09,w10,w11,w12,w13, W1h + (size_t)(ua +  89) * 224 + cq)
        LD7(w14,w15,w16,w17,w18,w19,w20, W1h + (size_t)(ua + 178) * 224 + cq)
        LD7(w21,w22,w23,w24,w25,w26,w27, W1h + (size_t)(ub      ) * 224 + cq)
        LD7(w28,w29,w30,w31,w32,w33,w34, W1h + (size_t)(ub +  89) * 224 + cq)
        LD7(w35,w36,w37,w38,w39,w40,w41, W1h + (size_t)(ub + 178) * 224 + cq)
        if (!vA) { Z7(w00,w01,w02,w03,w04,w05,w06) Z7(w07,w08,w09,w10,w11,w12,w13)
                   Z7(w14,w15,w16,w17,w18,w19,w20) }
        if (!vB) { Z7(w21,w22,w23,w24,w25,w26,w27) Z7(w28,w29,w30,w31,w32,w33,w34)
                   Z7(w35,w36,w37,w38,w39,w40,w41) }
        if (vA) { bA0 = b1s[ua]; bA1 = b1s[89 + ua]; bA2 = b1s[178 + ua]; }
        if (vB) { bB0 = b1s[ub]; bB1 = b1s[89 + ub]; bB2 = b1s[178 + ub]; }
    } else {
        const size_t c2 = 32 * q;
        LD4(w00,w01,w02,w03, W2h + (size_t)(s2     ) * 128 + c2)
        LD4(w04,w05,w06,w07, W2h + (size_t)(s2 + 32) * 128 + c2)
        LD4(w08,w09,w10,w11, W2h + (size_t)(s2 + 64) * 128 + c2)
        LD4(w12,w13,w14,w15, W2h + (size_t)(s2 + 16) * 128 + c2)
        LD4(w16,w17,w18,w19, W2h + (size_t)(s2 + 48) * 128 + c2)
        LD4(w20,w21,w22,w23, W2h + (size_t)(s2 + 80) * 128 + c2)
        vX = (s2 < 7);
        const int ux = vX ? 128 + s2 : 128;
        const size_t cq = 56 * q;
        LD7(w24,w25,w26,w27,w28,w29,w30, W0h + (size_t)(ux      ) * 224 + cq)
        LD7(w31,w32,w33,w34,w35,w36,w37, W0h + (size_t)(ux + 135) * 224 + cq)
        LD7(w38,w39,w40,w41,w42,w43,w44, W0h + (size_t)(ux + 270) * 224 + cq)
        if (!vX) { Z7(w24,w25,w26,w27,w28,w29,w30) Z7(w31,w32,w33,w34,w35,w36,w37)
                   Z7(w38,w39,w40,w41,w42,w43,w44) }
        bA0 = b2s[s2];      bA1 = b2s[32 + s2]; bA2 = b2s[64 + s2];
        bB0 = b2s[16 + s2]; bB1 = b2s[48 + s2]; bB2 = b2s[80 + s2];
        if (vX) { bX0 = b0c[ux]; bX1 = b0c[135 + ux]; bX2 = b0c[270 + ux]; }
    }
    PIN4(w00);PIN4(w01);PIN4(w02);PIN4(w03);PIN4(w04);PIN4(w05);PIN4(w06);
    PIN4(w07);PIN4(w08);PIN4(w09);PIN4(w10);PIN4(w11);PIN4(w12);PIN4(w13);
    PIN4(w14);PIN4(w15);PIN4(w16);PIN4(w17);PIN4(w18);PIN4(w19);PIN4(w20);
    PIN4(w21);PIN4(w22);PIN4(w23);PIN4(w24);PIN4(w25);PIN4(w26);PIN4(w27);
    PIN4(w28);PIN4(w29);PIN4(w30);PIN4(w31);PIN4(w32);PIN4(w33);PIN4(w34);
    PIN4(w35);PIN4(w36);PIN4(w37);PIN4(w38);PIN4(w39);PIN4(w40);PIN4(w41);
    PIN4(w42);PIN4(w43);PIN4(w44);

    const float* xb = x + (size_t)b * TTs * DINn;
    float* cfb = cfc + (size_t)b * TTs * 32;

    __syncthreads();
    if (xi >= 0) ((half_t*)&z0v[0][0])[xi] = (half_t)xb[xi];   // x(0)
    __syncthreads();

#pragma unroll 1
    for (int k = 0; k < TTs + 2; ++k) {
        const int p = k & 1;
        half_t* z0n = (half_t*)&z0v[p ^ 1][0];
        half_t* z1n = (half_t*)&z1v[p ^ 1][0];
        half_t* z2n = (half_t*)&z2v[p ^ 1][0];

        if (gL0) {
            // ---- L0: h0^{k+1} = f0(x_k, h0^k) over z0[p] ----
            const float4* zc = &z0v[p][q * 7];
            float4 f0 = zc[0], f1 = zc[1], f2 = zc[2], f3 = zc[3],
                   f4 = zc[4], f5 = zc[5], f6 = zc[6];
            float a0=0.f,a1=0.f,a2=0.f,a3=0.f,a4=0.f,a5=0.f;
            DR7(a0, w00,w01,w02,w03,w04,w05,w06)
            DR7(a1, w07,w08,w09,w10,w11,w12,w13)
            DR7(a2, w14,w15,w16,w17,w18,w19,w20)
            DR7(a3, w21,w22,w23,w24,w25,w26,w27)
            DR7(a4, w28,w29,w30,w31,w32,w33,w34)
            DR7(a5, w35,w36,w37,w38,w39,w40,w41)
            a0=qsum(a0); a1=qsum(a1); a2=qsum(a2);
            a3=qsum(a3); a4=qsum(a4); a5=qsum(a5);
            if (q == 0) {
                float h1v = cfc_comb(a0 + bA0, a1 + bA1, a2 + bA2);
                half_t hh1 = (half_t)h1v;
                z0n[64 + s0]  = hh1;
                z1n[s0]       = hh1;
                float h2v = cfc_comb(a3 + bB0, a4 + bB1, a5 + bB2);
                half_t hh2 = (half_t)h2v;
                z0n[128 + s0] = hh2;
                z1n[64 + s0]  = hh2;
            }
        } else if (gL1) {
            // ---- L1: h1^k = f1(h0^k, h1^{k-1}) over z1[p] ----
            const float4* zc = &z1v[p][q * 7];
            float4 f0 = zc[0], f1 = zc[1], f2 = zc[2], f3 = zc[3],
                   f4 = zc[4], f5 = zc[5], f6 = zc[6];
            float a0=0.f,a1=0.f,a2=0.f,a3=0.f,a4=0.f,a5=0.f;
            DR7(a0, w00,w01,w02,w03,w04,w05,w06)
            DR7(a1, w07,w08,w09,w10,w11,w12,w13)
            DR7(a2, w14,w15,w16,w17,w18,w19,w20)
            DR7(a3, w21,w22,w23,w24,w25,w26,w27)
            DR7(a4, w28,w29,w30,w31,w32,w33,w34)
            DR7(a5, w35,w36,w37,w38,w39,w40,w41)
            a0=qsum(a0); a1=qsum(a1); a2=qsum(a2);
            a3=qsum(a3); a4=qsum(a4); a5=qsum(a5);
            if (q == 0 && k >= 1) {
                if (s1 <= 44) {
                    float hv = cfc_comb(a0 + bA0, a1 + bA1, a2 + bA2);
                    half_t hh = (half_t)hv;
                    z1n[135 + s1] = hh;
                    z2n[s1]       = hh;
                }
                if (vB) {
                    float hv = cfc_comb(a3 + bB0, a4 + bB1, a5 + bB2);
                    half_t hh = (half_t)hv;
                    z1n[180 + s1] = hh;
                    z2n[45 + s1]  = hh;
                }
            }
        } else {
            // ---- wave 7: L2 h2^{k-1} + leftover L0 units + x staging ----
            int tn = k + 1; if (tn > TTs - 1) tn = TTs - 1;
            float xnext = xb[(size_t)tn * DINn + xi];
            {
                const float4* zc = &z2v[p][q * 4];
                float4 f0 = zc[0], f1 = zc[1], f2 = zc[2], f3 = zc[3];
                float a0=0.f,a1=0.f,a2=0.f,a3=0.f,a4=0.f,a5=0.f;
                DR4(a0, w00,w01,w02,w03)
                DR4(a1, w04,w05,w06,w07)
                DR4(a2, w08,w09,w10,w11)
                DR4(a3, w12,w13,w14,w15)
                DR4(a4, w16,w17,w18,w19)
                DR4(a5, w20,w21,w22,w23)
                a0=qsum(a0); a1=qsum(a1); a2=qsum(a2);
                a3=qsum(a3); a4=qsum(a4); a5=qsum(a5);
                if (q == 0 && k >= 2) {
                    float hv0 = cfc_comb(a0 + bA0, a1 + bA1, a2 + bA2);
                    z2n[89 + s2]  = (half_t)hv0;
                    cfb[(size_t)(k - 2) * 32 + s2] = hv0;
                    float hv1 = cfc_comb(a3 + bB0, a4 + bB1, a5 + bB2);
                    z2n[105 + s2] = (half_t)hv1;
                    cfb[(size_t)(k - 2) * 32 + 16 + s2] = hv1;
                }
            }
            if (vX) {   // leftover L0 units 128..134 (lanes with s2<7)
                const float4* zc = &z0v[p][q * 7];
                float4 f0 = zc[0], f1 = zc[1], f2 = zc[2], f3 = zc[3],
                       f4 = zc[4], f5 = zc[5], f6 = zc[6];
                float c0=0.f,c1=0.f,c2=0.f;
                DR7(c0, w24,w25,w26,w27,w28,w29,w30)
                DR7(c1, w31,w32,w33,w34,w35,w36,w37)
                DR7(c2, w38,w39,w40,w41,w42,w43,w44)
                c0=qsum(c0); c1=qsum(c1); c2=qsum(c2);
                if (q == 0) {
                    float hv = cfc_comb(c0 + bX0, c1 + bX1, c2 + bX2);
                    half_t hh = (half_t)hv;
                    z0n[192 + s2] = hh;
                    z1n[128 + s2] = hh;
                }
            }
            z0n[xi] = (half_t)xnext;   // x(k+1)
        }
        BAR();
    }
}

// ---------------- head: in-place gelu(cfc@Wh1.T+bh1)@Wh2.T + bh2 ----------------
__global__ __launch_bounds__(256) void k_head(float* io,
                                              const float* __restrict__ Wh1,
                                              const float* __restrict__ bh1,
                                              const float* __restrict__ Wh2T,
                                              const float* __restrict__ bh2)
{
    const int bt = blockIdx.x * 256 + threadIdx.x;
    float c32[32];
    const float4* cp = (const float4*)(io + (size_t)bt * 32);
#pragma unroll
    for (int k = 0; k < 8; ++k) {
        float4 v = cp[k];
        c32[4 * k] = v.x; c32[4 * k + 1] = v.y; c32[4 * k + 2] = v.z; c32[4 * k + 3] = v.w;
    }
    float acc[32];
#pragma unroll
    for (int o = 0; o < 32; ++o) acc[o] = bh2[o];
#pragma unroll 1
    for (int h = 0; h < HPn; ++h) {
        float ss = bh1[h];
        const float* w1r = Wh1 + (size_t)h * 32;
#pragma unroll
        for (int k = 0; k < 32; ++k) ss += c32[k] * w1r[k];
        float g = 0.5f * ss * (1.f + erff(ss * 0.70710678118654752440f));
        const float* w2r = Wh2T + (size_t)h * 32;
#pragma unroll
        for (int o = 0; o < 32; ++o) acc[o] += g * w2r[o];
    }
    float4* op = (float4*)(io + (size_t)bt * 32);
#pragma unroll
    for (int k = 0; k < 8; ++k) {
        float4 v;
        v.x = acc[4 * k]; v.y = acc[4 * k + 1]; v.z = acc[4 * k + 2]; v.w = acc[4 * k + 3];
        op[k] = v;
    }
}

// ---------------- launch ----------------
extern "C" void kernel_launch(void* const* d_in, const int* in_sizes, int n_in,
                              void* d_out, int out_size, void* d_ws, size_t ws_size,
                              hipStream_t stream)
{
    (void)in_sizes; (void)n_in; (void)out_size; (void)ws_size;
    const float* x      = (const float*)d_in[0];
    const float* Wp     = (const float*)d_in[1];
    const float* bp     = (const float*)d_in[2];
    const float* Wff1_0 = (const float*)d_in[3];
    const float* bff1_0 = (const float*)d_in[4];
    const float* Wff2_0 = (const float*)d_in[5];
    const float* bff2_0 = (const float*)d_in[6];
    const float* Wta_0  = (const float*)d_in[7];
    const float* bta_0  = (const float*)d_in[8];
    const float* Wtb_0  = (const float*)d_in[9];
    const float* btb_0  = (const float*)d_in[10];
    const unsigned char* mask_0 = (const unsigned char*)d_in[11];
    const float* Wff1_1 = (const float*)d_in[12];
    const float* bff1_1 = (const float*)d_in[13];
    const float* Wff2_1 = (const float*)d_in[14];
    const float* bff2_1 = (const float*)d_in[15];
    const float* Wta_1  = (const float*)d_in[16];
    const float* bta_1  = (const float*)d_in[17];
    const float* Wtb_1  = (const float*)d_in[18];
    const float* btb_1  = (const float*)d_in[19];
    const unsigned char* mask_1 = (const unsigned char*)d_in[20];
    const float* Wff1_2 = (const float*)d_in[21];
    const float* bff1_2 = (const float*)d_in[22];
    const float* Wff2_2 = (const float*)d_in[23];
    const float* bff2_2 = (const float*)d_in[24];
    const float* Wta_2  = (const float*)d_in[25];
    const float* bta_2  = (const float*)d_in[26];
    const float* Wtb_2  = (const float*)d_in[27];
    const float* btb_2  = (const float*)d_in[28];
    const unsigned char* mask_2 = (const unsigned char*)d_in[29];
    const float* Wh1    = (const float*)d_in[30];
    const float* bh1    = (const float*)d_in[31];
    const float* Wh2    = (const float*)d_in[32];
    const float* bh2    = (const float*)d_in[33];

    float* ws = (float*)d_ws;
    size_t o = 0;
    float* Wh0s = ws + o; o += (size_t)R0c * U0c;
    float* Wx0s = ws + o; o += (size_t)R0c * HPn;
    float* b0s  = ws + o; o += R0c; o += 3;
    float* Wcb  = ws + o; o += (size_t)R0c * DINn;
    float* b0c  = ws + o; o += R0c; o += 3;
    float* W1s  = ws + o; o += (size_t)R1c * C1c;
    float* b1s  = ws + o; o += R1c; o += 1;
    float* W2s  = ws + o; o += (size_t)R2c * C2c;
    float* b2s  = ws + o; o += R2c;
    float* Wh2T = ws + o; o += (size_t)HPn * 32;
    half_t* W0h = (half_t*)(ws + o); o += (size_t)R0c * 224 / 2;
    half_t* W1h = (half_t*)(ws + o); o += (size_t)R1c * 224 / 2;
    half_t* W2h = (half_t*)(ws + o); o += (size_t)R2c * 128 / 2;

    k_stack<<<128, 256, 0, stream>>>(Wff1_0, bff1_0, Wff2_0, bff2_0, Wta_0, bta_0, Wtb_0, btb_0,
                                     mask_0, U0c, C0c, HPn, Wx0s, Wh0s, b0s);
    k_stack<<<64, 256, 0, stream>>>(Wff1_1, bff1_1, Wff2_1, bff2_1, Wta_1, bta_1, Wtb_1, btb_1,
                                    mask_1, U1c, C1c, C1c, W1s, W1s, b1s);
    k_stack<<<16, 256, 0, stream>>>(Wff1_2, bff1_2, Wff2_2, bff2_2, Wta_2, bta_2, Wtb_2, btb_2,
                                    mask_2, U2c, C2c, C2c, W2s, W2s, b2s);
    k_comb<<<R0c, DINn, 0, stream>>>(Wx0s, Wp, Wcb);
    k_biasc<<<32, 256, 0, stream>>>(Wx0s, bp, b0s, b0c, Wh2, Wh2T);
    k_pack<<<320, 256, 0, stream>>>(Wcb, Wh0s, W1s, W2s, W0h, W1h, W2h);
    k_scan<<<BBn, 512, 0, stream>>>(W0h, W1h, W2h, b0c, b1s, b2s, x, (float*)d_out);
    k_head<<<(int)(BTn / 256), 256, 0, stream>>>((float*)d_out, Wh1, bh1, Wh2T, bh2);
}